// Round 5
// baseline (470.954 us; speedup 1.0000x reference)
//
#include <hip/hip_runtime.h>
#include <hip/hip_fp16.h>
#include <math.h>

#define TT 8192
#define LOG2T 13
#define CC 64
#define BB 64
#define NTHREADS 256
#define TWO_PI 6.28318530717958647692f

// ============================================================================
// Four-step FFT: 8192 = N1(64) * N2(128).  t = n1 + 64*n2, k = 128*k1 + k2.
//  - kA/kC (unchanged): LDS-free lane-cooperative 128-pt FFTs.
//  - kB (R5): ZERO-LDS / ZERO-BARRIER MFMA DFT. Wave owns 16 channels
//    (columns) and computes ALL 64 rows:
//      * X B-fragments read once from global (shared across all m-tiles).
//      * fwd D-layout (row=4lg+j, col=lr) == inverse B-layout (k=4lg+i, n=lr)
//        -> forward output feeds inverse directly in registers (f32->f16 pack
//        only); the Y LDS exchange is gone.
//      * A-fragments: F = W64^{-mk}; kt=0 by HW trig, kt+1 = kt * i^{-m}
//        (exact swap/negate rotation, since W64^{-16m} = i^{-m}).
//    All MFMA lane mappings identical to the R4-verified conventions.
// ws  (kernel A out, aliased onto d_out): [b][k2][n1][c]   (half2)
// ws2 (kernel B out, in d_ws):            [b][n1][k2][c]   (half2)
// Mask handling: masked-out channels skip phase replacement in B, so the
// round-trip DFT->IDFT (x64, normalized in kC by 1/8192) reproduces input.
// ============================================================================

// ---- compile-time twiddle machinery (kA/kC) --------------------------------
constexpr double PI_D = 3.141592653589793238462643383279502884;
constexpr double ct_sin(double x) {  // |x| <= pi, Taylor
  double x2 = x * x, t = x, s = x;
  for (int k = 1; k <= 13; ++k) { t *= -x2 / ((2.0 * k) * (2.0 * k + 1.0)); s += t; }
  return s;
}
constexpr double ct_cos(double x) {
  double x2 = x * x, t = 1.0, s = 1.0;
  for (int k = 1; k <= 13; ++k) { t *= -x2 / ((2.0 * k - 1.0) * (2.0 * k)); s += t; }
  return s;
}
struct Tw128 { float c[128]; float s[128]; };
constexpr Tw128 mk_tw() {
  Tw128 t{};
  for (int k = 0; k < 128; ++k) {
    int kk = (k < 64) ? k : k - 128;             // reduce to [-pi, pi)
    double a = (2.0 * PI_D / 128.0) * kk;        // +angle; fwd uses -s
    t.c[k] = (float)ct_cos(a);
    t.s[k] = (float)ct_sin(a);
  }
  return t;
}
constexpr Tw128 TW = mk_tw();

constexpr int br5(int x) {
  return ((x & 1) << 4) | ((x & 2) << 2) | (x & 4) | ((x & 8) >> 2) | ((x & 16) >> 4);
}

__device__ __forceinline__ float2 cmul(float2 a, float co, float si) {
  return make_float2(a.x * co - a.y * si, a.x * si + a.y * co);
}
// raw HW sin/cos: input in REVOLUTIONS (D = sin/cos(S0 * 2pi))
__device__ __forceinline__ float hw_sin(float f) {
  float r; asm("v_sin_f32 %0, %1" : "=v"(r) : "v"(f)); return r;
}
__device__ __forceinline__ float hw_cos(float f) {
  float r; asm("v_cos_f32 %0, %1" : "=v"(r) : "v"(f)); return r;
}

// DIF stage over NB butterflies, span HLF; twiddle exp(-/+ i*pi*j/HLF).
template<int HLF, int NB, bool INV>
__device__ __forceinline__ void dif_stage(float2* X) {
  #pragma unroll
  for (int m = 0; m < NB; ++m) {
    const int j = m & (HLF - 1);
    const int i1 = ((m & ~(HLF - 1)) << 1) | j;
    const int i2 = i1 + HLF;
    const int k = (64 / HLF) * j;
    const float2 u = X[i1], v = X[i2];
    X[i1] = make_float2(u.x + v.x, u.y + v.y);
    const float dx = u.x - v.x, dy = u.y - v.y;
    if (k == 0) {
      X[i2] = make_float2(dx, dy);
    } else {
      const float co = TW.c[k], si = INV ? TW.s[k] : -TW.s[k];
      X[i2] = make_float2(dx * co - dy * si, dx * si + dy * co);
    }
  }
}

// ---- MFMA helpers (kB) ------------------------------------------------------
typedef __attribute__((ext_vector_type(4))) _Float16 v4h;
typedef __attribute__((ext_vector_type(4))) float v4f;
typedef __attribute__((ext_vector_type(2))) unsigned int u32x2;

__device__ __forceinline__ v4h mk4h(unsigned int lo, unsigned int hi) {
  u32x2 u; u.x = lo; u.y = hi;
  return __builtin_bit_cast(v4h, u);
}
__device__ __forceinline__ unsigned pkh(float a, float b) {
  return __builtin_bit_cast(unsigned, __floats2half2_rn(a, b));
}

// ---- Kernel A: per (b, n1): 64 channels x 128-pt forward FFT ---------------
// Wave = 16 channels x 4 q-lanes (lane bits 4..5 = q). Lane q loads rows
// n2 = 32q..32q+31; radix-4 cross combine via shfl_xor(32), shfl_xor(16).
__global__ __launch_bounds__(NTHREADS) void kA(const float* __restrict__ wav,
                                               __half2* __restrict__ ws) {
  const int b = blockIdx.x >> 6, n1 = blockIdx.x & 63;
  const int tid = threadIdx.x, w = tid >> 6, l = tid & 63;
  const int q = l >> 4, cl = l & 15, c = (w << 4) | cl;
  const int SQ = ((q & 1) << 1) | (q >> 1);       // br2(q): {0,2,1,3}
  const bool hiQ = (l & 32) != 0, loQ = (l & 16) != 0;

  const float* wp = wav + ((size_t)b * TT + n1) * CC + c + (size_t)q * (32 * 64 * CC);
  float x[32];
  #pragma unroll
  for (int r = 0; r < 32; ++r) x[r] = wp[(size_t)r * (64 * CC)];

  // cross radix-4 combine + per-lane combine twiddle W128^{-SQ*r}
  const float sqn = (float)SQ * (-1.0f / 128.0f);
  float2 X[32];
  #pragma unroll
  for (int r = 0; r < 32; ++r) {
    const float t = __shfl_xor(x[r], 32, 64);
    const float u = hiQ ? (t - x[r]) : (x[r] + t);
    const float t2 = __shfl_xor(u, 16, 64);
    const float re = hiQ ? (loQ ? t2 : u) : (loQ ? (t2 - u) : (u + t2));
    const float im = hiQ ? (loQ ? u : -t2) : 0.0f;
    if (r == 0) { X[0] = make_float2(re, im); }
    else {
      const float arg = sqn * (float)r;
      const float si = hw_sin(arg), co = hw_cos(arg);
      X[r] = make_float2(re * co - im * si, re * si + im * co);
    }
  }

  // 5 register-resident DIF stages (compile-time twiddles).
  dif_stage<16, 16, false>(X); dif_stage<8, 16, false>(X);
  dif_stage<4, 16, false>(X);  dif_stage<2, 16, false>(X);
  dif_stage<1, 16, false>(X);

  // Output twiddle W8192^{-n1*k2}, k2 = 4r + SQ, position m = br5(r).
  float cd, sd, c0, s0;
  __sincosf(-(TWO_PI / 2048.0f) * (float)n1, &sd, &cd);
  __sincosf(-(TWO_PI / 8192.0f) * (float)(n1 * SQ), &s0, &c0);
  float wc = c0, wsn = s0;
  __half2* wsp = ws + (size_t)b * (128 * 4096) + (size_t)n1 * 64 + c +
                 (size_t)SQ * 4096;
  #pragma unroll
  for (int r = 0; r < 32; ++r) {
    const int m = br5(r);
    const float2 v = cmul(X[m], wc, wsn);
    wsp[(size_t)r * 16384] = __floats2half2_rn(v.x, v.y);
    const float nc = wc * cd - wsn * sd;
    wsn = wc * sd + wsn * cd; wc = nc;
  }
}

// ---- Kernel B (R5): per (b, k2): zero-LDS zero-barrier MFMA DFT pair -------
// 4 waves/block; wave w owns channels c = 16w..16w+15 and all 64 rows.
// v_mfma_f32_16x16x16_f16 layouts (R4-verified):
//   A[m][k]: m=lane&15, k=4*(lane>>4)+i;  B[k][n]: k=4*(lane>>4)+i, n=lane&15;
//   D[m][n]: m=4*(lane>>4)+j, n=lane&15.
__global__ __launch_bounds__(NTHREADS) void kB(const __half2* __restrict__ ws,
                                               const float* __restrict__ ph,
                                               const float* __restrict__ mask,
                                               __half2* __restrict__ ws2) {
  const int b = blockIdx.x >> 7, k2 = blockIdx.x & 127;
  const int tid = threadIdx.x, w = tid >> 6, l = tid & 63;
  const int lr = l & 15, lg = l >> 4;
  const int c = 16 * w + lr;

  // 1) X B-fragment loads: element i of tile kt = X[4lg+i+16kt][c]
  const unsigned* gx = (const unsigned*)ws + (size_t)blockIdx.x * 4096 + c;
  unsigned xd[16];
  #pragma unroll
  for (int kt = 0; kt < 4; ++kt)
    #pragma unroll
    for (int i = 0; i < 4; ++i)
      xd[4 * kt + i] = gx[(4 * lg + i + 16 * kt) * 64];

  // 2) A fragments: F[m][k] = W64^{-mk} = (cos th, -sin th), th=(mk&63)/64 rev.
  //    kt=0 by trig; kt->kt+1 via exact rotation * i^{-m} (m&3 = lr&3).
  const int r3 = lr & 3;
  const bool swp = (r3 & 1) != 0;
  const unsigned nm = (r3 >= 2) ? 0x80008000u : 0u;
  unsigned ARl[4][4], ARh[4][4], AIl[4][4], AIh[4][4];
  #pragma unroll
  for (int mt = 0; mt < 4; ++mt) {
    const int m = 16 * mt + lr;
    float fr[4], fi[4];
    #pragma unroll
    for (int i = 0; i < 4; ++i) {
      const int p = (m * (4 * lg + i)) & 63;
      const float th = (float)p * (1.0f / 64.0f);
      fr[i] = hw_cos(th);
      fi[i] = -hw_sin(th);
    }
    ARl[mt][0] = pkh(fr[0], fr[1]); ARh[mt][0] = pkh(fr[2], fr[3]);
    AIl[mt][0] = pkh(fi[0], fi[1]); AIh[mt][0] = pkh(fi[2], fi[3]);
    #pragma unroll
    for (int kt = 1; kt < 4; ++kt) {
      const unsigned Rl = ARl[mt][kt - 1], Rh = ARh[mt][kt - 1];
      const unsigned Il = AIl[mt][kt - 1], Ih = AIh[mt][kt - 1];
      const unsigned Rsl = swp ? Il : Rl, Rsh = swp ? Ih : Rh;
      const unsigned Isl = swp ? (Rl ^ 0x80008000u) : Il;
      const unsigned Ish = swp ? (Rh ^ 0x80008000u) : Ih;
      ARl[mt][kt] = Rsl ^ nm; ARh[mt][kt] = Rsh ^ nm;
      AIl[mt][kt] = Isl ^ nm; AIh[mt][kt] = Ish ^ nm;
    }
  }

  // 3) unpack X into (Xr, Xi, -Xi) f16 fragments
  unsigned Xr[4][2], Xi[4][2], mXi[4][2];
  #pragma unroll
  for (int kt = 0; kt < 4; ++kt) {
    const unsigned d0 = xd[4 * kt + 0], d1 = xd[4 * kt + 1];
    const unsigned d2 = xd[4 * kt + 2], d3 = xd[4 * kt + 3];
    Xr[kt][0] = __builtin_amdgcn_perm(d1, d0, 0x05040100u);
    Xr[kt][1] = __builtin_amdgcn_perm(d3, d2, 0x05040100u);
    Xi[kt][0] = __builtin_amdgcn_perm(d1, d0, 0x07060302u);
    Xi[kt][1] = __builtin_amdgcn_perm(d3, d2, 0x07060302u);
    mXi[kt][0] = Xi[kt][0] ^ 0x80008000u;
    mXi[kt][1] = Xi[kt][1] ^ 0x80008000u;
  }

  // 4) forward DFT: Y = F * X  (Yr = Ar.Xr + Ai.(-Xi), Yi = Ar.Xi + Ai.Xr)
  const v4f z4 = {0.f, 0.f, 0.f, 0.f};
  v4f yR[4] = {z4, z4, z4, z4}, yI[4] = {z4, z4, z4, z4};
  #pragma unroll
  for (int mt = 0; mt < 4; ++mt) {
    #pragma unroll
    for (int kt = 0; kt < 4; ++kt) {
      const v4h ar = mk4h(ARl[mt][kt], ARh[mt][kt]);
      const v4h ai = mk4h(AIl[mt][kt], AIh[mt][kt]);
      yR[mt] = __builtin_amdgcn_mfma_f32_16x16x16f16(ar, mk4h(Xr[kt][0], Xr[kt][1]), yR[mt], 0, 0, 0);
      yR[mt] = __builtin_amdgcn_mfma_f32_16x16x16f16(ai, mk4h(mXi[kt][0], mXi[kt][1]), yR[mt], 0, 0, 0);
      yI[mt] = __builtin_amdgcn_mfma_f32_16x16x16f16(ar, mk4h(Xi[kt][0], Xi[kt][1]), yI[mt], 0, 0, 0);
      yI[mt] = __builtin_amdgcn_mfma_f32_16x16x16f16(ai, mk4h(Xr[kt][0], Xr[kt][1]), yI[mt], 0, 0, 0);
    }
  }

  // 5) pointwise phase replacement; D row j of tile mt holds k1 = 16mt+4lg+j
  const bool rep = mask[(b << 6) + c] < 0.5f;
  if (rep) {
    const float* php = ph + ((size_t)b * TT + k2) * CC + c;
    #pragma unroll
    for (int mt = 0; mt < 4; ++mt) {
      #pragma unroll
      for (int j = 0; j < 4; ++j) {
        const int k1 = 16 * mt + 4 * lg + j;
        const float phi = php[(size_t)k1 * 8192];  // revolutions
        const float yr = yR[mt][j], yi = yI[mt][j];
        const float amp = sqrtf(yr * yr + yi * yi);
        yR[mt][j] = amp * hw_cos(phi);
        yI[mt][j] = amp * hw_sin(phi);
      }
    }
  }

  // 6) D-layout == next B-layout: pack Y to f16 fragments directly
  unsigned Yr[4][2], Yi[4][2], mYr[4][2];
  #pragma unroll
  for (int t = 0; t < 4; ++t) {
    Yr[t][0] = pkh(yR[t][0], yR[t][1]); Yr[t][1] = pkh(yR[t][2], yR[t][3]);
    Yi[t][0] = pkh(yI[t][0], yI[t][1]); Yi[t][1] = pkh(yI[t][2], yI[t][3]);
    mYr[t][0] = Yr[t][0] ^ 0x80008000u; mYr[t][1] = Yr[t][1] ^ 0x80008000u;
  }

  // 7) inverse DFT: Z = conj(F) * Y  (Zr = Ar.Yr + Ai.Yi, Zi = Ar.Yi + Ai.(-Yr))
  v4f zR[4] = {z4, z4, z4, z4}, zI[4] = {z4, z4, z4, z4};
  #pragma unroll
  for (int mt = 0; mt < 4; ++mt) {
    #pragma unroll
    for (int kt = 0; kt < 4; ++kt) {
      const v4h ar = mk4h(ARl[mt][kt], ARh[mt][kt]);
      const v4h ai = mk4h(AIl[mt][kt], AIh[mt][kt]);
      zR[mt] = __builtin_amdgcn_mfma_f32_16x16x16f16(ar, mk4h(Yr[kt][0], Yr[kt][1]), zR[mt], 0, 0, 0);
      zR[mt] = __builtin_amdgcn_mfma_f32_16x16x16f16(ai, mk4h(Yi[kt][0], Yi[kt][1]), zR[mt], 0, 0, 0);
      zI[mt] = __builtin_amdgcn_mfma_f32_16x16x16f16(ar, mk4h(Yi[kt][0], Yi[kt][1]), zI[mt], 0, 0, 0);
      zI[mt] = __builtin_amdgcn_mfma_f32_16x16x16f16(ai, mk4h(mYr[kt][0], mYr[kt][1]), zI[mt], 0, 0, 0);
    }
  }

  // 8) outer twiddle W8192^{+n1*k2} + store ws2[b][n1][k2][c]
  unsigned* wout = (unsigned*)ws2 + (size_t)b * (64 * 8192) + (size_t)k2 * 64 + c;
  #pragma unroll
  for (int mt = 0; mt < 4; ++mt) {
    #pragma unroll
    for (int j = 0; j < 4; ++j) {
      const int n1 = 16 * mt + 4 * lg + j;
      const float th = (float)(n1 * k2) * (1.0f / 8192.0f);  // < 1 rev, exact
      const float co = hw_cos(th), si = hw_sin(th);
      const float zr = zR[mt][j] * co - zI[mt][j] * si;
      const float zi = zR[mt][j] * si + zI[mt][j] * co;
      wout[(size_t)n1 * 8192] = pkh(zr, zi);
    }
  }
}

// ---- Kernel C: per (b, n1): 64 channels x 128-pt inverse FFT ---------------
__global__ __launch_bounds__(NTHREADS) void kC(const __half2* __restrict__ ws2,
                                               float* __restrict__ out) {
  const int b = blockIdx.x >> 6, n1 = blockIdx.x & 63;
  const int tid = threadIdx.x, w = tid >> 6, l = tid & 63;
  const int q = l >> 4, cl = l & 15, c = (w << 4) | cl;
  const int SQ = ((q & 1) << 1) | (q >> 1);
  const bool hiQ = (l & 32) != 0, loQ = (l & 16) != 0;

  const __half2* rp = ws2 + (size_t)blockIdx.x * 8192 + (size_t)(32 * q) * 64 + c;
  float2 x[32];
  #pragma unroll
  for (int r = 0; r < 32; ++r) x[r] = __half22float2(rp[(size_t)r * 64]);

  // cross radix-4 combine (inverse), per-lane twiddle W128^{+SQ*r}
  const float sqp = (float)SQ * (1.0f / 128.0f);
  float2 X[32];
  #pragma unroll
  for (int r = 0; r < 32; ++r) {
    const float tre = __shfl_xor(x[r].x, 32, 64);
    const float tim = __shfl_xor(x[r].y, 32, 64);
    const float ure = hiQ ? (tre - x[r].x) : (x[r].x + tre);
    const float uim = hiQ ? (tim - x[r].y) : (x[r].y + tim);
    const float t2re = __shfl_xor(ure, 16, 64);
    const float t2im = __shfl_xor(uim, 16, 64);
    const float re = hiQ ? (loQ ? (t2re + uim) : (ure - t2im))
                         : (loQ ? (t2re - ure) : (ure + t2re));
    const float im = hiQ ? (loQ ? (t2im - ure) : (uim + t2re))
                         : (loQ ? (t2im - uim) : (uim + t2im));
    if (r == 0) { X[0] = make_float2(re, im); }
    else {
      const float arg = sqp * (float)r;
      const float si = hw_sin(arg), co = hw_cos(arg);
      X[r] = make_float2(re * co - im * si, re * si + im * co);
    }
  }

  // 5 register-resident inverse DIF stages
  dif_stage<16, 16, true>(X); dif_stage<8, 16, true>(X);
  dif_stage<4, 16, true>(X);  dif_stage<2, 16, true>(X);
  dif_stage<1, 16, true>(X);

  // reg m=br5(r) holds n2 = 4r + SQ: out[b][n1 + 64*n2][c] = Re / 8192
  float* op = out + (size_t)b * (TT * CC) + (size_t)n1 * CC + c + (size_t)SQ * 4096;
  #pragma unroll
  for (int r = 0; r < 32; ++r) {
    const int m = br5(r);
    op[(size_t)r * 16384] = X[m].x * (1.0f / 8192.0f);
  }
}

// ---- Fallback (R1 single-kernel, correct but slow) if ws is too small ----
__global__ __launch_bounds__(NTHREADS) void ft_surrogate_fallback(
    const float* __restrict__ wav, const float* __restrict__ ph,
    const float* __restrict__ mask, float* __restrict__ out) {
  const int bc = blockIdx.x;
  const int c = bc & (CC - 1);
  const int b = bc >> 6;
  const int tid = threadIdx.x;
  const size_t base = (size_t)b * TT * CC + (size_t)c;
  const float m = mask[bc];
  if (!(m < 0.5f)) {
    for (int t = tid; t < TT; t += NTHREADS)
      out[base + (size_t)t * CC] = wav[base + (size_t)t * CC];
    return;
  }
  __shared__ float2 X[TT];
  for (int t = tid; t < TT; t += NTHREADS)
    X[t] = make_float2(wav[base + (size_t)t * CC], 0.0f);
  __syncthreads();
  for (int len = TT, hlf = TT >> 1; len >= 2; len >>= 1, hlf >>= 1) {
    const float ang_scale = -TWO_PI / (float)len;
    for (int it = 0; it < (TT / 2) / NTHREADS; ++it) {
      const int m2 = tid + it * NTHREADS;
      const int j = m2 & (hlf - 1);
      const int i1 = ((m2 & ~(hlf - 1)) << 1) | j;
      const int i2 = i1 + hlf;
      float2 u = X[i1], v = X[i2];
      float ar = u.x + v.x, ai = u.y + v.y;
      float br = u.x - v.x, bi = u.y - v.y;
      float s, cth;
      __sincosf(ang_scale * (float)j, &s, &cth);
      X[i1] = make_float2(ar, ai);
      X[i2] = make_float2(br * cth - bi * s, br * s + bi * cth);
    }
    __syncthreads();
  }
  for (int p = tid; p < TT; p += NTHREADS) {
    const int k = (int)(__brev((unsigned)p) >> (32 - LOG2T));
    float2 v = X[p];
    float amp = sqrtf(v.x * v.x + v.y * v.y);
    float phi = ph[(size_t)b * TT * CC + (size_t)k * CC + (size_t)c];
    float s, cth;
    __sincosf(TWO_PI * phi, &s, &cth);
    X[p] = make_float2(amp * cth, amp * s);
  }
  __syncthreads();
  for (int len = 2, hlf = 1; len <= TT; len <<= 1, hlf <<= 1) {
    const float ang_scale = TWO_PI / (float)len;
    for (int it = 0; it < (TT / 2) / NTHREADS; ++it) {
      const int m2 = tid + it * NTHREADS;
      const int j = m2 & (hlf - 1);
      const int i1 = ((m2 & ~(hlf - 1)) << 1) | j;
      const int i2 = i1 + hlf;
      float s, cth;
      __sincosf(ang_scale * (float)j, &s, &cth);
      float2 u = X[i1], w = X[i2];
      float vr = w.x * cth - w.y * s;
      float vi = w.x * s + w.y * cth;
      X[i1] = make_float2(u.x + vr, u.y + vi);
      X[i2] = make_float2(u.x - vr, u.y - vi);
    }
    __syncthreads();
  }
  const float invN = 1.0f / (float)TT;
  for (int t = tid; t < TT; t += NTHREADS)
    out[base + (size_t)t * CC] = X[t].x * invN;
}

extern "C" void kernel_launch(void* const* d_in, const int* in_sizes, int n_in,
                              void* d_out, int out_size, void* d_ws, size_t ws_size,
                              hipStream_t stream) {
  const float* wav  = (const float*)d_in[0];
  const float* ph   = (const float*)d_in[1];
  const float* mask = (const float*)d_in[2];
  const size_t need = (size_t)BB * TT * CC * sizeof(__half2);  // 128 MB

  if (ws_size >= need) {
    // ws (A->B) aliases d_out; ws2 (B->C) lives in d_ws. Distinct kernels on
    // the same stream order the hazards.
    __half2* ws  = (__half2*)d_out;
    __half2* ws2 = (__half2*)d_ws;
    kA<<<dim3(BB * 64), dim3(NTHREADS), 0, stream>>>(wav, ws);
    kB<<<dim3(BB * 128), dim3(NTHREADS), 0, stream>>>(ws, ph, mask, ws2);
    kC<<<dim3(BB * 64), dim3(NTHREADS), 0, stream>>>(ws2, (float*)d_out);
  } else {
    ft_surrogate_fallback<<<dim3(BB * CC), dim3(NTHREADS), 0, stream>>>(
        wav, ph, mask, (float*)d_out);
  }
}